// Round 1
// baseline (767.756 us; speedup 1.0000x reference)
//
#include <hip/hip_runtime.h>

// NodeFeat: out[n,d,c] (c stride 1, d stride 9, n stride 576), c = hop*3 + part
//   hop0: x * {1, rsqrt(deg), sqrt(deg)}
//   hop1: (1/deg) * spmm(hop0)
//   hop2: (1/deg) * spmm(hop1) - hop0
// spmm(v)[i] = sum over edges e with row[e]==i of v[col[e]]
// Strategy: build CSR over `row` each launch (hist -> scan -> counting sort),
// then one wave per destination node; lane = feature d (D=64). Per edge one
// coalesced 256B gather (hop1) / 768B (hop2). Edge ids + per-source scalars
// broadcast via __shfl to kill dependent-load chains.

static inline size_t ws_align(size_t x) { return (x + 255) & ~(size_t)255; }

__global__ __launch_bounds__(256) void k_hist(const int* __restrict__ row,
                                              int* __restrict__ counts, int E) {
  int e = blockIdx.x * 256 + threadIdx.x;
  if (e < E) atomicAdd(&counts[row[e]], 1);
}

__global__ __launch_bounds__(1024) void k_blocksum(const int* __restrict__ counts,
                                                   int* __restrict__ partial, int N) {
  __shared__ int wsum[16];
  int t = threadIdx.x;
  int idx = blockIdx.x * 1024 + t;
  int v = (idx < N) ? counts[idx] : 0;
  for (int off = 32; off; off >>= 1) v += __shfl_down(v, off, 64);
  if ((t & 63) == 0) wsum[t >> 6] = v;
  __syncthreads();
  if (t == 0) {
    int s = 0;
#pragma unroll
    for (int k = 0; k < 16; ++k) s += wsum[k];
    partial[blockIdx.x] = s;
  }
}

__global__ void k_scanpartial(const int* __restrict__ partial,
                              int* __restrict__ pscan, int NB) {
  __shared__ int buf[1024];
  int t = threadIdx.x;
  for (int k = t; k < NB; k += blockDim.x) buf[k] = partial[k];
  __syncthreads();
  if (t == 0) {
    int run = 0;
    for (int k = 0; k < NB; ++k) { int v = buf[k]; buf[k] = run; run += v; }
  }
  __syncthreads();
  for (int k = t; k < NB; k += blockDim.x) pscan[k] = buf[k];
}

__global__ __launch_bounds__(1024) void k_scanapply(const int* __restrict__ counts,
    const int* __restrict__ pscan, int* __restrict__ offsets,
    int* __restrict__ cursor, int N) {
  __shared__ int wsum[16];
  int t = threadIdx.x, lane = t & 63, wv = t >> 6;
  int idx = blockIdx.x * 1024 + t;
  int v = (idx < N) ? counts[idx] : 0;
  int x = v;
#pragma unroll
  for (int off = 1; off < 64; off <<= 1) {
    int y = __shfl_up(x, off, 64);
    if (lane >= off) x += y;
  }
  if (lane == 63) wsum[wv] = x;
  __syncthreads();
  if (t == 0) {
    int run = 0;
#pragma unroll
    for (int k = 0; k < 16; ++k) { int s = wsum[k]; wsum[k] = run; run += s; }
  }
  __syncthreads();
  int excl = pscan[blockIdx.x] + wsum[wv] + x - v;
  if (idx < N) { offsets[idx] = excl; cursor[idx] = excl; }
}

__global__ __launch_bounds__(256) void k_scatter(const int* __restrict__ row,
    const int* __restrict__ col, int* __restrict__ cursor,
    int* __restrict__ csr, int E) {
  int e = blockIdx.x * 256 + threadIdx.x;
  if (e < E) {
    int i = row[e];
    int pos = atomicAdd(&cursor[i], 1);
    csr[pos] = col[e];
  }
}

// One wave per node. lane = feature d in [0,64).
__global__ __launch_bounds__(256) void k_hop1(const float* __restrict__ x,
    const float* __restrict__ deg, const int* __restrict__ offsets,
    const int* __restrict__ counts, const int* __restrict__ csr,
    float* __restrict__ out, float* __restrict__ xs1, int N) {
  int w = (blockIdx.x * 256 + threadIdx.x) >> 6;
  int lane = threadIdx.x & 63;
  if (w >= N) return;
  int i = w;
  float degi = deg[i];
  float degrev = 1.0f / degi;
  int beg = offsets[i];
  int end = beg + counts[i];
  float s0 = 0.f, s1 = 0.f, s2 = 0.f;
  for (int base = beg; base < end; base += 64) {
    int n = end - base; if (n > 64) n = 64;
    int jv = 0; float rv = 0.f, qv = 0.f;
    if (lane < n) {
      jv = csr[base + lane];
      float dv = deg[jv];
      rv = rsqrtf(dv);
      qv = dv * rv;           // sqrt(dv)
    }
    for (int t = 0; t < n; ++t) {
      int j   = __shfl(jv, t, 64);
      float r = __shfl(rv, t, 64);
      float q = __shfl(qv, t, 64);
      float v = x[(size_t)j * 64 + lane];
      s0 += v;
      s1 += v * r;
      s2 += v * q;
    }
  }
  float xv = x[(size_t)i * 64 + lane];
  float ri = rsqrtf(degi);
  float qi = degi * ri;
  float a0 = xv, a1 = xv * ri, a2 = xv * qi;
  float b0 = s0 * degrev, b1 = s1 * degrev, b2 = s2 * degrev;
  size_t ob = (size_t)i * 576 + (size_t)lane * 9;
  out[ob + 0] = a0; out[ob + 1] = a1; out[ob + 2] = a2;
  out[ob + 3] = b0; out[ob + 4] = b1; out[ob + 5] = b2;
  if (xs1) {
    size_t xb = (size_t)i * 192 + lane;
    xs1[xb] = b0; xs1[xb + 64] = b1; xs1[xb + 128] = b2;
  }
}

// MODE 0: gather xs1 packed [N,192] from ws. MODE 1: gather from out (strided).
template <int MODE>
__global__ __launch_bounds__(256) void k_hop2(const float* __restrict__ x,
    const float* __restrict__ deg, const int* __restrict__ offsets,
    const int* __restrict__ counts, const int* __restrict__ csr,
    float* __restrict__ out, const float* __restrict__ src, int N) {
  int w = (blockIdx.x * 256 + threadIdx.x) >> 6;
  int lane = threadIdx.x & 63;
  if (w >= N) return;
  int i = w;
  float degi = deg[i];
  float degrev = 1.0f / degi;
  int beg = offsets[i];
  int end = beg + counts[i];
  float a0 = 0.f, a1 = 0.f, a2 = 0.f;
  for (int base = beg; base < end; base += 64) {
    int n = end - base; if (n > 64) n = 64;
    int jv = 0;
    if (lane < n) jv = csr[base + lane];
    for (int t = 0; t < n; ++t) {
      int j = __shfl(jv, t, 64);
      if (MODE == 0) {
        size_t b = (size_t)j * 192 + lane;
        a0 += src[b];
        a1 += src[b + 64];
        a2 += src[b + 128];
      } else {
        size_t b = (size_t)j * 576 + (size_t)lane * 9 + 3;
        a0 += src[b];
        a1 += src[b + 1];
        a2 += src[b + 2];
      }
    }
  }
  float xv = x[(size_t)i * 64 + lane];
  float ri = rsqrtf(degi);
  float qi = degi * ri;
  float c0 = a0 * degrev - xv;
  float c1 = a1 * degrev - xv * ri;
  float c2 = a2 * degrev - xv * qi;
  size_t ob = (size_t)i * 576 + (size_t)lane * 9;
  out[ob + 6] = c0; out[ob + 7] = c1; out[ob + 8] = c2;
}

extern "C" void kernel_launch(void* const* d_in, const int* in_sizes, int n_in,
                              void* d_out, int out_size, void* d_ws, size_t ws_size,
                              hipStream_t stream) {
  const float* x   = (const float*)d_in[0];
  const float* deg = (const float*)d_in[1];
  const int*   row = (const int*)d_in[2];
  const int*   col = (const int*)d_in[3];
  float* out = (float*)d_out;

  int N = in_sizes[1];       // deg has N elements
  int E = in_sizes[2];       // row has E elements
  int NB = (N + 1023) / 1024;

  char* ws = (char*)d_ws;
  size_t off = 0;
  int* counts  = (int*)(ws + off); off = ws_align(off + (size_t)N * 4);
  int* offsets = (int*)(ws + off); off = ws_align(off + (size_t)N * 4);
  int* cursor  = (int*)(ws + off); off = ws_align(off + (size_t)N * 4);
  int* partial = (int*)(ws + off); off = ws_align(off + (size_t)NB * 4);
  int* pscan   = (int*)(ws + off); off = ws_align(off + (size_t)NB * 4);
  int* csr     = (int*)(ws + off); off = ws_align(off + (size_t)E * 4);
  size_t xs1_bytes = (size_t)N * 192 * 4;
  bool packed = (off + xs1_bytes) <= ws_size;
  float* xs1 = packed ? (float*)(ws + off) : nullptr;

  hipMemsetAsync(counts, 0, (size_t)N * 4, stream);
  k_hist<<<(E + 255) / 256, 256, 0, stream>>>(row, counts, E);
  k_blocksum<<<NB, 1024, 0, stream>>>(counts, partial, N);
  k_scanpartial<<<1, 128, 0, stream>>>(partial, pscan, NB);
  k_scanapply<<<NB, 1024, 0, stream>>>(counts, pscan, offsets, cursor, N);
  k_scatter<<<(E + 255) / 256, 256, 0, stream>>>(row, col, cursor, csr, E);

  int hopBlocks = (N + 3) / 4;   // 4 waves per 256-thread block, 1 wave per node
  k_hop1<<<hopBlocks, 256, 0, stream>>>(x, deg, offsets, counts, csr, out, xs1, N);
  if (packed) {
    k_hop2<0><<<hopBlocks, 256, 0, stream>>>(x, deg, offsets, counts, csr, out, xs1, N);
  } else {
    k_hop2<1><<<hopBlocks, 256, 0, stream>>>(x, deg, offsets, counts, csr, out, out, N);
  }
}

// Round 2
// 655.280 us; speedup vs baseline: 1.1716x; 1.1716x over previous
//
#include <hip/hip_runtime.h>

// NodeFeat: out[n,d,c] (c stride 1, d stride 9, n stride 576), c = hop*3 + part
//   hop0: x * {1, rsqrt(deg), sqrt(deg)}
//   hop1: (1/deg) * spmm(hop0)
//   hop2: (1/deg) * spmm(hop1) - hop0
// R1 changes: bf16 gather paths (x and xs1), planar bf16 xs1 in ws, and a
// single full-line writer of `out` (k_prop2 writes all 9 floats/lane) to kill
// the partial-line RMW seen in R0 (WRITE_SIZE 225MB for 77MB of payload).

static inline size_t ws_align(size_t x) { return (x + 255) & ~(size_t)255; }

__device__ inline float bf2f(unsigned short s) {
  return __uint_as_float(((unsigned)s) << 16);
}
__device__ inline unsigned short f2bf(float f) {
  unsigned u = __float_as_uint(f);
  unsigned r = u + 0x7fff + ((u >> 16) & 1);   // round-to-nearest-even
  return (unsigned short)(r >> 16);
}

__global__ __launch_bounds__(256) void k_hist(const int* __restrict__ row,
                                              int* __restrict__ counts, int E) {
  int e = blockIdx.x * 256 + threadIdx.x;
  if (e < E) atomicAdd(&counts[row[e]], 1);
}

__global__ __launch_bounds__(1024) void k_blocksum(const int* __restrict__ counts,
                                                   int* __restrict__ partial, int N) {
  __shared__ int wsum[16];
  int t = threadIdx.x;
  int idx = blockIdx.x * 1024 + t;
  int v = (idx < N) ? counts[idx] : 0;
  for (int off = 32; off; off >>= 1) v += __shfl_down(v, off, 64);
  if ((t & 63) == 0) wsum[t >> 6] = v;
  __syncthreads();
  if (t == 0) {
    int s = 0;
#pragma unroll
    for (int k = 0; k < 16; ++k) s += wsum[k];
    partial[blockIdx.x] = s;
  }
}

__global__ void k_scanpartial(const int* __restrict__ partial,
                              int* __restrict__ pscan, int NB) {
  __shared__ int buf[1024];
  int t = threadIdx.x;
  for (int k = t; k < NB; k += blockDim.x) buf[k] = partial[k];
  __syncthreads();
  if (t == 0) {
    int run = 0;
    for (int k = 0; k < NB; ++k) { int v = buf[k]; buf[k] = run; run += v; }
  }
  __syncthreads();
  for (int k = t; k < NB; k += blockDim.x) pscan[k] = buf[k];
}

__global__ __launch_bounds__(1024) void k_scanapply(const int* __restrict__ counts,
    const int* __restrict__ pscan, int* __restrict__ offsets,
    int* __restrict__ cursor, int N) {
  __shared__ int wsum[16];
  int t = threadIdx.x, lane = t & 63, wv = t >> 6;
  int idx = blockIdx.x * 1024 + t;
  int v = (idx < N) ? counts[idx] : 0;
  int x = v;
#pragma unroll
  for (int off = 1; off < 64; off <<= 1) {
    int y = __shfl_up(x, off, 64);
    if (lane >= off) x += y;
  }
  if (lane == 63) wsum[wv] = x;
  __syncthreads();
  if (t == 0) {
    int run = 0;
#pragma unroll
    for (int k = 0; k < 16; ++k) { int s = wsum[k]; wsum[k] = run; run += s; }
  }
  __syncthreads();
  int excl = pscan[blockIdx.x] + wsum[wv] + x - v;
  if (idx < N) { offsets[idx] = excl; cursor[idx] = excl; }
}

__global__ __launch_bounds__(256) void k_scatter(const int* __restrict__ row,
    const int* __restrict__ col, int* __restrict__ cursor,
    int* __restrict__ csr, int E) {
  int e = blockIdx.x * 256 + threadIdx.x;
  if (e < E) {
    int i = row[e];
    int pos = atomicAdd(&cursor[i], 1);
    csr[pos] = col[e];
  }
}
// After k_scatter, cursor[i] == offsets[i] + counts[i]  (used as `ends`).

// x fp32 [N*64] -> bf16 [N*64], 4 elems/thread
__global__ __launch_bounds__(256) void k_cvt(const float4* __restrict__ x,
                                             uint2* __restrict__ xb, int n4) {
  int i = blockIdx.x * 256 + threadIdx.x;
  if (i >= n4) return;
  float4 v = x[i];
  uint2 p;
  p.x = (unsigned)f2bf(v.x) | ((unsigned)f2bf(v.y) << 16);
  p.y = (unsigned)f2bf(v.z) | ((unsigned)f2bf(v.w) << 16);
  xb[i] = p;
}

// hop1: one wave per node, lane = feature. Gathers bf16 x; writes 3 bf16
// planes of xs1 (plane stride N*64). No writes to `out`.
__global__ __launch_bounds__(256) void k_prop1(const unsigned short* __restrict__ xb,
    const float* __restrict__ deg, const int* __restrict__ offsets,
    const int* __restrict__ ends, const int* __restrict__ csr,
    unsigned short* __restrict__ xs1, int N) {
  int w = (blockIdx.x * 256 + threadIdx.x) >> 6;
  int lane = threadIdx.x & 63;
  if (w >= N) return;
  int beg = offsets[w];
  int end = ends[w];
  float s0 = 0.f, s1 = 0.f, s2 = 0.f;
  for (int base = beg; base < end; base += 64) {
    int n = end - base; if (n > 64) n = 64;
    int jv = 0; float rv = 0.f, qv = 0.f;
    if (lane < n) {
      jv = csr[base + lane];
      float dv = deg[jv];
      rv = rsqrtf(dv);
      qv = dv * rv;               // sqrt(dv)
    }
    for (int t = 0; t < n; ++t) {
      int j   = __shfl(jv, t, 64);
      float r = __shfl(rv, t, 64);
      float q = __shfl(qv, t, 64);
      float v = bf2f(xb[(size_t)j * 64 + lane]);
      s0 += v;
      s1 += v * r;
      s2 += v * q;
    }
  }
  float dr = 1.0f / deg[w];
  size_t b = (size_t)w * 64 + lane;
  size_t P = (size_t)N * 64;
  xs1[b]         = f2bf(s0 * dr);
  xs1[b + P]     = f2bf(s1 * dr);
  xs1[b + 2 * P] = f2bf(s2 * dr);
}

// hop2 + full epilogue: gathers bf16 xs1 planes, recomputes hop0 from fp32 x,
// reads own hop1 row, writes ALL 9 floats per (n,d) -> full-line stores.
__global__ __launch_bounds__(256) void k_prop2(const float* __restrict__ x,
    const float* __restrict__ deg, const int* __restrict__ offsets,
    const int* __restrict__ ends, const int* __restrict__ csr,
    const unsigned short* __restrict__ xs1, float* __restrict__ out, int N) {
  int w = (blockIdx.x * 256 + threadIdx.x) >> 6;
  int lane = threadIdx.x & 63;
  if (w >= N) return;
  size_t P = (size_t)N * 64;
  int beg = offsets[w];
  int end = ends[w];
  float a0 = 0.f, a1 = 0.f, a2 = 0.f;
  for (int base = beg; base < end; base += 64) {
    int n = end - base; if (n > 64) n = 64;
    int jv = 0;
    if (lane < n) jv = csr[base + lane];
    for (int t = 0; t < n; ++t) {
      int j = __shfl(jv, t, 64);
      size_t b = (size_t)j * 64 + lane;
      a0 += bf2f(xs1[b]);
      a1 += bf2f(xs1[b + P]);
      a2 += bf2f(xs1[b + 2 * P]);
    }
  }
  float degi = deg[w];
  float dr = 1.0f / degi;
  float ri = rsqrtf(degi);
  float qi = degi * ri;
  size_t b = (size_t)w * 64 + lane;
  float xv = x[b];
  float h0 = bf2f(xs1[b]);
  float h1 = bf2f(xs1[b + P]);
  float h2 = bf2f(xs1[b + 2 * P]);
  float o0 = xv, o1 = xv * ri, o2 = xv * qi;
  float* op = out + (size_t)w * 576 + (size_t)lane * 9;
  op[0] = o0; op[1] = o1; op[2] = o2;
  op[3] = h0; op[4] = h1; op[5] = h2;
  op[6] = a0 * dr - o0;
  op[7] = a1 * dr - o1;
  op[8] = a2 * dr - o2;
}

extern "C" void kernel_launch(void* const* d_in, const int* in_sizes, int n_in,
                              void* d_out, int out_size, void* d_ws, size_t ws_size,
                              hipStream_t stream) {
  const float* x   = (const float*)d_in[0];
  const float* deg = (const float*)d_in[1];
  const int*   row = (const int*)d_in[2];
  const int*   col = (const int*)d_in[3];
  float* out = (float*)d_out;

  int N = in_sizes[1];       // deg has N elements
  int E = in_sizes[2];       // row has E elements
  int NB = (N + 1023) / 1024;

  char* ws = (char*)d_ws;
  size_t off = 0;
  int* counts  = (int*)(ws + off); off = ws_align(off + (size_t)N * 4);
  int* offsets = (int*)(ws + off); off = ws_align(off + (size_t)N * 4);
  int* cursor  = (int*)(ws + off); off = ws_align(off + (size_t)N * 4);
  int* partial = (int*)(ws + off); off = ws_align(off + (size_t)NB * 4);
  int* pscan   = (int*)(ws + off); off = ws_align(off + (size_t)NB * 4);
  int* csr     = (int*)(ws + off); off = ws_align(off + (size_t)E * 4);
  unsigned short* xb  = (unsigned short*)(ws + off); off = ws_align(off + (size_t)N * 64 * 2);
  unsigned short* xs1 = (unsigned short*)(ws + off); off = ws_align(off + (size_t)N * 64 * 3 * 2);
  // total ~59 MB; R0 confirmed ws_size >= ~85 MB (packed path taken)

  int n4 = N * 16;  // N*64/4 float4 groups
  k_cvt<<<(n4 + 255) / 256, 256, 0, stream>>>((const float4*)x, (uint2*)xb, n4);

  hipMemsetAsync(counts, 0, (size_t)N * 4, stream);
  k_hist<<<(E + 255) / 256, 256, 0, stream>>>(row, counts, E);
  k_blocksum<<<NB, 1024, 0, stream>>>(counts, partial, N);
  k_scanpartial<<<1, 128, 0, stream>>>(partial, pscan, NB);
  k_scanapply<<<NB, 1024, 0, stream>>>(counts, pscan, offsets, cursor, N);
  k_scatter<<<(E + 255) / 256, 256, 0, stream>>>(row, col, cursor, csr, E);

  int hopBlocks = (N + 3) / 4;   // 4 waves/block, 1 wave per node
  k_prop1<<<hopBlocks, 256, 0, stream>>>(xb, deg, offsets, cursor, csr, xs1, N);
  k_prop2<<<hopBlocks, 256, 0, stream>>>(x, deg, offsets, cursor, csr, xs1, out, N);
}